// Round 7
// baseline (334.559 us; speedup 1.0000x reference)
//
#include <hip/hip_runtime.h>

// Problem constants (fixed by setup_inputs): B=32, C=256, H=W=64
#define BATCH 32
#define CHAN  256
#define HGT   64
#define WID   64
#define HW    4096   // HGT*WID

// Single fused kernel. Grid = 2048 blocks x 256 threads; each block handles
// 4 consecutive planes (one per wave) of one batch.
// Ordering is the whole trick: every lane issues its 16 float4 plane loads
// FIRST (64 payload VGPRs), then the block scatter-builds A[b] in LDS
// (VALU + ds_add work that hides the ~900-cyc global-load latency), then one
// barrier, then FMAs against LDS-resident A using already-landed registers.
__global__ __launch_bounds__(256, 4) void fused_kernel(
        const float* __restrict__ data,     // [B, C, H, W] fp32
        const float* __restrict__ offset,   // [B, 2, H, W] fp32
        const float* __restrict__ ts_ptr,   // scalar fp32
        float* __restrict__ out)            // [B, C] fp32
{
    __shared__ float A[HW];                 // 16 KiB weight map
    const int tid        = threadIdx.x;
    const int base_plane = blockIdx.x << 2;     // 4 consecutive planes
    const int b          = base_plane >> 8;     // 4 | 256 -> no batch straddle
    const int wv         = tid >> 6;
    const int lane       = tid & 63;

    // ---- Phase 0: issue ALL data loads for this wave's plane ----
    const float* plane = data + (size_t)(base_plane + wv) * HW;
    const int o = lane << 2;                    // lane*4 floats
    float4 d[16];
    #pragma unroll
    for (int k = 0; k < 16; ++k)
        d[k] = *reinterpret_cast<const float4*>(plane + k * 256 + o);

    // ---- Phase 1: zero A, scatter bilinear weights (hides load latency) ----
    #pragma unroll
    for (int k = 0; k < 16; ++k) A[k * 256 + tid] = 0.0f;
    __syncthreads();

    float ts = ts_ptr[0];
    ts = fminf(fmaxf(ts, 0.001f), 0.01f);

    const float* off_y = offset + (size_t)b * 2 * HW;   // offset[b,0]
    const float* off_x = off_y + HW;                    // offset[b,1]

    #pragma unroll
    for (int it = 0; it < 16; ++it) {
        const int p = it * 256 + tid;
        const int i = p >> 6;
        const int j = p & 63;
        const float dy = off_y[p];
        const float dx = off_x[p];
        // reference: y = clip(i + (ts*offset)*H, 0, H-1)
        float y = fminf(fmaxf((float)i + ts * dy * 64.0f, 0.0f), 63.0f);
        float x = fminf(fmaxf((float)j + ts * dx * 64.0f, 0.0f), 63.0f);
        int y0 = (int)floorf(y); y0 = min(max(y0, 0), HGT - 2);
        int x0 = (int)floorf(x); x0 = min(max(x0, 0), WID - 2);
        const float wy = y - (float)y0;
        const float wx = x - (float)x0;
        const int base = (y0 << 6) + x0;
        atomicAdd(&A[base],           (1.0f - wy) * (1.0f - wx));
        atomicAdd(&A[base + 1],       (1.0f - wy) * wx);
        atomicAdd(&A[base + WID],     wy * (1.0f - wx));
        atomicAdd(&A[base + WID + 1], wy * wx);
    }
    __syncthreads();

    // ---- Phase 2: dot(LDS A, registers) ----
    float s0 = 0.0f, s1 = 0.0f, s2 = 0.0f, s3 = 0.0f;
    #pragma unroll
    for (int k = 0; k < 16; k += 4) {
        const float4 a0 = *reinterpret_cast<const float4*>(&A[(k + 0) * 256 + o]);
        const float4 a1 = *reinterpret_cast<const float4*>(&A[(k + 1) * 256 + o]);
        const float4 a2 = *reinterpret_cast<const float4*>(&A[(k + 2) * 256 + o]);
        const float4 a3 = *reinterpret_cast<const float4*>(&A[(k + 3) * 256 + o]);
        s0 = fmaf(a0.x, d[k+0].x, s0); s0 = fmaf(a0.y, d[k+0].y, s0);
        s0 = fmaf(a0.z, d[k+0].z, s0); s0 = fmaf(a0.w, d[k+0].w, s0);
        s1 = fmaf(a1.x, d[k+1].x, s1); s1 = fmaf(a1.y, d[k+1].y, s1);
        s1 = fmaf(a1.z, d[k+1].z, s1); s1 = fmaf(a1.w, d[k+1].w, s1);
        s2 = fmaf(a2.x, d[k+2].x, s2); s2 = fmaf(a2.y, d[k+2].y, s2);
        s2 = fmaf(a2.z, d[k+2].z, s2); s2 = fmaf(a2.w, d[k+2].w, s2);
        s3 = fmaf(a3.x, d[k+3].x, s3); s3 = fmaf(a3.y, d[k+3].y, s3);
        s3 = fmaf(a3.z, d[k+3].z, s3); s3 = fmaf(a3.w, d[k+3].w, s3);
    }
    float s = (s0 + s1) + (s2 + s3);

    // wave-64 shuffle reduce; lane 0 stores (mean folded here: A was raw sums)
    #pragma unroll
    for (int off = 32; off > 0; off >>= 1)
        s += __shfl_down(s, off, 64);

    if (lane == 0) out[base_plane + wv] = s * (1.0f / (float)HW);
}

extern "C" void kernel_launch(void* const* d_in, const int* in_sizes, int n_in,
                              void* d_out, int out_size, void* d_ws, size_t ws_size,
                              hipStream_t stream) {
    const float* data   = (const float*)d_in[0];  // fp32 [32,256,64,64]
    const float* offset = (const float*)d_in[1];  // fp32 [32,2,64,64]
    const float* ts     = (const float*)d_in[2];  // fp32 scalar
    float* out = (float*)d_out;                   // [32, 256] fp32

    fused_kernel<<<(BATCH * CHAN) / 4, 256, 0, stream>>>(data, offset, ts, out);
}